// Round 4
// baseline (352.302 us; speedup 1.0000x reference)
//
#include <hip/hip_runtime.h>
#include <hip/hip_bf16.h>
#include <math.h>

typedef unsigned short u16;
typedef __attribute__((ext_vector_type(8))) short short8;
typedef __attribute__((ext_vector_type(4))) float float4v;

#define MFMA_BF16(a, b, c) __builtin_amdgcn_mfma_f32_16x16x32_bf16((a), (b), (c), 0, 0, 0)

typedef const __attribute__((address_space(1))) void* gas_ptr;
typedef __attribute__((address_space(3))) void* las_ptr;

__device__ __forceinline__ u16 f2bf(float f) {
  __hip_bfloat16 h = __float2bfloat16(f);
  return __builtin_bit_cast(u16, h);
}

__device__ __forceinline__ float bf2f(u16 v) {
  return __builtin_bit_cast(float, (unsigned)v << 16);
}

__device__ __forceinline__ void load_lds16(const u16* g, u16* l) {
  __builtin_amdgcn_global_load_lds((gas_ptr)g, (las_ptr)l, 16, 0, 0);
}

// XCD-aware chunked block swizzle (T1). Bijective when nwg % 8 == 0.
__device__ __forceinline__ int xcd_swz(int bid, int nwg) {
  return (bid & 7) * (nwg >> 3) + (bid >> 3);
}

// ---------------------------------------------------------------------------
// 256x256 tile, BK=64, 8 waves (2M x 4N), "minimum 2-phase" schedule (T3):
//   stage(next tile) -> ds_read+MFMA(cur) -> one __syncthreads per K-tile.
// LDS: per matrix per buffer the K-tile is stored as TWO K-panels
// [2][256][32] u16 so ds_read row-stride is 64B (2-way bank alias = free)
// instead of 128B (16-way conflict). Staging stays gload_lds-linear:
// each 1KB wave-load fills rows rg*16..+16, cols p*32..+32 of panel p.
// Total LDS = 2buf x (A 32KB + B 32KB) = 128 KiB -> 1 block/CU; the
// latency hiding is the 64-MFMA/wave compute phase (2 waves/SIMD).
// ---------------------------------------------------------------------------
__device__ __forceinline__ void gemm_mainloop256(
    const u16* __restrict__ A, const u16* __restrict__ Bt,
    int kb, int kend, int lda, int ldb,
    int m0, int n0, u16* lds, float4v acc[8][4])
{
  const int tid = threadIdx.x;
  const int w = tid >> 6, lane = tid & 63;
  const int wr = w >> 2, wc = w & 3;            // wave grid 2M x 4N
  const int lr = lane & 15, lk = (lane >> 4) * 8;
  const int r4 = lane >> 2, c4 = (lane & 3) * 8; // staging row/col-in-group

  auto stage = [&](int buf, int k0) {
#pragma unroll
    for (int c = 0; c < 4; ++c) {
      int ri = w + c * 8;            // 0..31: which 1KB region
      int p = ri >> 4, rg = ri & 15; // panel, row-group
      int row = rg * 16 + r4;
      int col = p * 32 + c4;
      u16* dA = lds + buf * 16384 + p * 8192 + rg * 512;
      u16* dB = lds + 32768 + buf * 16384 + p * 8192 + rg * 512;
      load_lds16(A + (size_t)(m0 + row) * lda + k0 + col, dA);
      load_lds16(Bt + (size_t)(n0 + row) * ldb + k0 + col, dB);
    }
  };

  int cur = 0;
  stage(0, kb);
  __syncthreads();
  for (int k0 = kb; k0 < kend; k0 += 64) {
    if (k0 + 64 < kend) stage(cur ^ 1, k0 + 64);  // prefetch next K-tile
    const u16* As = lds + cur * 16384;
    const u16* Bs = lds + 32768 + cur * 16384;
#pragma unroll
    for (int ks = 0; ks < 2; ++ks) {   // the two K-panels (K=32 each)
      short8 af[8], bfr[4];
#pragma unroll
      for (int mt = 0; mt < 8; ++mt)
        af[mt] = *(const short8*)&As[ks * 8192 + (wr * 128 + mt * 16 + lr) * 32 + lk];
#pragma unroll
      for (int nt = 0; nt < 4; ++nt)
        bfr[nt] = *(const short8*)&Bs[ks * 8192 + (wc * 64 + nt * 16 + lr) * 32 + lk];
      __builtin_amdgcn_s_setprio(1);
#pragma unroll
      for (int mt = 0; mt < 8; ++mt)
#pragma unroll
        for (int nt = 0; nt < 4; ++nt)
          acc[mt][nt] = MFMA_BF16(af[mt], bfr[nt], acc[mt][nt]);
      __builtin_amdgcn_s_setprio(0);
    }
    __syncthreads();  // drains my stage loads + everyone's ds_reads
    cur ^= 1;
  }
}

#define ACC_INIT(acc)                                              \
  _Pragma("unroll") for (int mt = 0; mt < 8; ++mt)                 \
  _Pragma("unroll") for (int nt = 0; nt < 4; ++nt)                 \
      acc[mt][nt] = (float4v){0.f, 0.f, 0.f, 0.f};

// ---------------------------------------------------------------------------
// GEMM 1: QKV projection. M=8192, N=1536, K=512. 32x6=192 blocks, swizzled.
// ---------------------------------------------------------------------------
__global__ __launch_bounds__(512, 2) void gemm_qkv(
    const u16* __restrict__ A, const u16* __restrict__ Bt,
    const float* __restrict__ bq, const float* __restrict__ bk, const float* __restrict__ bv,
    u16* __restrict__ qo, u16* __restrict__ ko, u16* __restrict__ vto)
{
  extern __shared__ u16 lds[];
  float4v acc[8][4];
  ACC_INIT(acc);
  const int s = xcd_swz(blockIdx.x, 192);
  const int m0 = (s / 6) * 256, n0 = (s % 6) * 256;
  gemm_mainloop256(A, Bt, 0, 512, 512, 512, m0, n0, lds, acc);
  const int tid = threadIdx.x, w = tid >> 6, lane = tid & 63;
  const int wr = w >> 2, wc = w & 3, lr = lane & 15, lg = lane >> 4;
#pragma unroll
  for (int mt = 0; mt < 8; ++mt) {
#pragma unroll
    for (int nt = 0; nt < 4; ++nt) {
      int n = n0 + wc * 64 + nt * 16 + lr;
#pragma unroll
      for (int r = 0; r < 4; ++r) {
        int i = m0 + wr * 128 + mt * 16 + lg * 4 + r;
        float v = acc[mt][nt][r];
        if (n < 512) {
          qo[(size_t)i * 512 + n] = f2bf(v + bq[n]);
        } else if (n < 1024) {
          ko[(size_t)i * 512 + (n - 512)] = f2bf(v + bk[n - 512]);
        } else {
          int bb = i >> 12, t = i & 4095;
          vto[((size_t)(bb * 512 + (n - 1024))) * 4096 + t] = f2bf(v + bv[n - 1024]);
        }
      }
    }
  }
}

// ---------------------------------------------------------------------------
// Attention pass 1: P = exp(QK^T/sqrt(d) - ds*dist), causal, bf16 out.
// 256-row tiles, triangular grid: 136 tiles x 2 batches. No swizzle
// (round-2 A/B: concentrating same-row tiles on one XCD hurt). Diagonal
// tiles write p=0 for j>i so P is fully defined for j < (tm+1)*256.
// ---------------------------------------------------------------------------
__global__ __launch_bounds__(512, 2) void gemm_qk_p(
    const u16* __restrict__ q, const u16* __restrict__ k,
    const float* __restrict__ dsp,
    u16* __restrict__ P, float* __restrict__ l)
{
  extern __shared__ u16 lds[];
  float4v acc[8][4];
  ACC_INIT(acc);
  const int b = blockIdx.y;
  const u16* qb = q + (size_t)b * 4096 * 512;
  const u16* kb = k + (size_t)b * 4096 * 512;
  u16* Pb = P + (size_t)b * 4096 * 4096;
  float* lb = l + b * 4096;
  int idx = blockIdx.x;
  int tm = (int)((sqrtf(8.0f * (float)idx + 1.0f) - 1.0f) * 0.5f);
  while ((tm + 1) * (tm + 2) / 2 <= idx) ++tm;
  while (tm * (tm + 1) / 2 > idx) --tm;
  int tn = idx - tm * (tm + 1) / 2;
  const int m0 = tm * 256, n0 = tn * 256;
  gemm_mainloop256(qb, kb, 0, 512, 512, 512, m0, n0, lds, acc);
  const int tid = threadIdx.x, w = tid >> 6, lane = tid & 63;
  const int wr = w >> 2, wc = w & 3, lr = lane & 15, lg = lane >> 4;
  const float invs = 0.04419417382415922f;   // 1/sqrt(512)
  const float dsi = dsp[0] * invs;
  const float L2E = 1.4426950408889634f;
  float rs[8][4];
#pragma unroll
  for (int mt = 0; mt < 8; ++mt)
#pragma unroll
    for (int r = 0; r < 4; ++r) rs[mt][r] = 0.f;
#pragma unroll
  for (int mt = 0; mt < 8; ++mt) {
#pragma unroll
    for (int nt = 0; nt < 4; ++nt) {
      int j = n0 + wc * 64 + nt * 16 + lr;
#pragma unroll
      for (int r = 0; r < 4; ++r) {
        int i = m0 + wr * 128 + mt * 16 + lg * 4 + r;
        float x = acc[mt][nt][r] * invs - dsi * fabsf((float)(i - j));
        float p = (j > i) ? 0.f : exp2f(x * L2E);
        Pb[(size_t)i * 4096 + j] = f2bf(p);
        rs[mt][r] += p;
      }
    }
  }
#pragma unroll
  for (int mt = 0; mt < 8; ++mt) {
#pragma unroll
    for (int r = 0; r < 4; ++r) {
      float v = rs[mt][r];
#pragma unroll
      for (int off = 1; off < 16; off <<= 1) v += __shfl_xor(v, off, 64);
      if (lr == 0)
        atomicAdd(&lb[m0 + wr * 128 + mt * 16 + lg * 4 + r], v);
    }
  }
}

// ---------------------------------------------------------------------------
// Attention pass 2: P @ V, 256-row tiles, K-chunks of <=1024.
// chunks per tm = (tm>>2)+1 (max 4), 40 (tm,chunk) pairs x 2 ncols x 2 b
// = 160 blocks, swizzled. chunk 0 -> y0 fp32; 1/2/3 -> y1/y2/y3 bf16
// (valid for rows >=1024/2048/3072; ln1 reads conditionally, no memset).
// ---------------------------------------------------------------------------
__global__ __launch_bounds__(512, 2) void gemm_pv(
    const u16* __restrict__ P, const u16* __restrict__ vt,
    float* __restrict__ y0, u16* __restrict__ y1,
    u16* __restrict__ y2, u16* __restrict__ y3)
{
  extern __shared__ u16 lds[];
  float4v acc[8][4];
  ACC_INIT(acc);
  const int s = xcd_swz(blockIdx.x, 160);
  const int b = s / 80;
  const int t2 = s % 80;
  const int xb = t2 & 1;
  int rem = t2 >> 1;          // 0..39: (tm, chunk) pair
  const u16* Pb = P + (size_t)b * 4096 * 4096;
  const u16* vb = vt + (size_t)b * 512 * 4096;
  int tm = 0, cpt = 1;
  while (rem >= cpt) { rem -= cpt; ++tm; cpt = (tm >> 2) + 1; }
  const int m0 = tm * 256, n0 = xb * 256;
  const int kb = rem * 1024;
  const int kfull = (tm + 1) * 256;
  const int kend = (kb + 1024 < kfull) ? (kb + 1024) : kfull;
  gemm_mainloop256(Pb, vb, kb, kend, 4096, 4096, m0, n0, lds, acc);
  const int tid = threadIdx.x, w = tid >> 6, lane = tid & 63;
  const int wr = w >> 2, wc = w & 3, lr = lane & 15, lg = lane >> 4;
  const size_t bofs = (size_t)b * 4096 * 512;
#pragma unroll
  for (int mt = 0; mt < 8; ++mt) {
#pragma unroll
    for (int nt = 0; nt < 4; ++nt) {
      int n = n0 + wc * 64 + nt * 16 + lr;
#pragma unroll
      for (int r = 0; r < 4; ++r) {
        int i = m0 + wr * 128 + mt * 16 + lg * 4 + r;
        size_t o = bofs + (size_t)i * 512 + n;
        float v = acc[mt][nt][r];
        if (rem == 0)      y0[o] = v;
        else if (rem == 1) y1[o] = f2bf(v);
        else if (rem == 2) y2[o] = f2bf(v);
        else               y3[o] = f2bf(v);
      }
    }
  }
}

// ---------------------------------------------------------------------------
// GEMM: FFN1 (relu epilogue). M=8192, N=2048: 32x8=256 blocks, swizzled.
// ---------------------------------------------------------------------------
__global__ __launch_bounds__(512, 2) void gemm_ffn1(
    const u16* __restrict__ A, const u16* __restrict__ Bt,
    const float* __restrict__ b1, u16* __restrict__ h)
{
  extern __shared__ u16 lds[];
  float4v acc[8][4];
  ACC_INIT(acc);
  const int s = xcd_swz(blockIdx.x, 256);
  const int m0 = (s / 8) * 256, n0 = (s % 8) * 256;
  gemm_mainloop256(A, Bt, 0, 512, 512, 512, m0, n0, lds, acc);
  const int tid = threadIdx.x, w = tid >> 6, lane = tid & 63;
  const int wr = w >> 2, wc = w & 3, lr = lane & 15, lg = lane >> 4;
#pragma unroll
  for (int mt = 0; mt < 8; ++mt) {
#pragma unroll
    for (int nt = 0; nt < 4; ++nt) {
      int n = n0 + wc * 64 + nt * 16 + lr;
#pragma unroll
      for (int r = 0; r < 4; ++r) {
        int i = m0 + wr * 128 + mt * 16 + lg * 4 + r;
        h[(size_t)i * 2048 + n] = f2bf(fmaxf(acc[mt][nt][r] + b1[n], 0.f));
      }
    }
  }
}

// ---------------------------------------------------------------------------
// GEMM: FFN2, K=2048 split x4 (512 each): 32m x 2n x 4chunk = 256 blocks,
// swizzled. chunk 0 -> f0 fp32; 1/2/3 -> f1/f2/f3 bf16 (always written,
// no memset). LN2 sums all four.
// ---------------------------------------------------------------------------
__global__ __launch_bounds__(512, 2) void gemm_ffn2(
    const u16* __restrict__ A, const u16* __restrict__ Bt,
    float* __restrict__ f0, u16* __restrict__ f1,
    u16* __restrict__ f2, u16* __restrict__ f3)
{
  extern __shared__ u16 lds[];
  float4v acc[8][4];
  ACC_INIT(acc);
  const int s = xcd_swz(blockIdx.x, 256);
  const int m0 = (s / 8) * 256;
  const int sub = s % 8;
  const int n0 = (sub >> 2) * 256;
  const int zz = sub & 3;
  const int kb = zz * 512;
  gemm_mainloop256(A, Bt, kb, kb + 512, 2048, 2048, m0, n0, lds, acc);
  const int tid = threadIdx.x, w = tid >> 6, lane = tid & 63;
  const int wr = w >> 2, wc = w & 3, lr = lane & 15, lg = lane >> 4;
#pragma unroll
  for (int mt = 0; mt < 8; ++mt) {
#pragma unroll
    for (int nt = 0; nt < 4; ++nt) {
      int n = n0 + wc * 64 + nt * 16 + lr;
#pragma unroll
      for (int r = 0; r < 4; ++r) {
        int i = m0 + wr * 128 + mt * 16 + lg * 4 + r;
        size_t o = (size_t)i * 512 + n;
        float v = acc[mt][nt][r];
        if (zz == 0)      f0[o] = v;
        else if (zz == 1) f1[o] = f2bf(v);
        else if (zz == 2) f2[o] = f2bf(v);
        else              f3[o] = f2bf(v);
      }
    }
  }
}

// ---------------------------------------------------------------------------
// LN1: x = LN((y0 [+y1 +y2 +y3 row-conditional])/l + tokens); fp32+bf16 out.
// ---------------------------------------------------------------------------
__global__ __launch_bounds__(256) void ln1_kernel(
    const float* __restrict__ y0, const u16* __restrict__ y1,
    const u16* __restrict__ y2, const u16* __restrict__ y3,
    const float* __restrict__ lsum, const float* __restrict__ tok,
    const float* __restrict__ g, const float* __restrict__ be,
    float* __restrict__ of, u16* __restrict__ ob)
{
  const int row = blockIdx.x * 4 + (threadIdx.x >> 6);
  const int lane = threadIdx.x & 63;
  const int rloc = row & 4095;  // row within batch
  const size_t base = (size_t)row * 512 + lane * 8;
  const float linv = 1.0f / lsum[row];
  float v[8];
#pragma unroll
  for (int t = 0; t < 8; ++t) v[t] = y0[base + t];
  if (rloc >= 1024) {
#pragma unroll
    for (int t = 0; t < 8; ++t) v[t] += bf2f(y1[base + t]);
  }
  if (rloc >= 2048) {
#pragma unroll
    for (int t = 0; t < 8; ++t) v[t] += bf2f(y2[base + t]);
  }
  if (rloc >= 3072) {
#pragma unroll
    for (int t = 0; t < 8; ++t) v[t] += bf2f(y3[base + t]);
  }
#pragma unroll
  for (int t = 0; t < 8; ++t) v[t] = v[t] * linv + tok[base + t];
  float s = 0.f;
#pragma unroll
  for (int t = 0; t < 8; ++t) s += v[t];
#pragma unroll
  for (int off = 1; off < 64; off <<= 1) s += __shfl_xor(s, off, 64);
  const float mu = s * (1.0f / 512.0f);
  float qv = 0.f;
#pragma unroll
  for (int t = 0; t < 8; ++t) { float d = v[t] - mu; qv += d * d; }
#pragma unroll
  for (int off = 1; off < 64; off <<= 1) qv += __shfl_xor(qv, off, 64);
  const float rs = rsqrtf(qv * (1.0f / 512.0f) + 1e-5f);
  const int cb = lane * 8;
#pragma unroll
  for (int t = 0; t < 8; ++t) {
    float xv = (v[t] - mu) * rs * g[cb + t] + be[cb + t];
    of[base + t] = xv;
    ob[base + t] = f2bf(xv);
  }
}

// ---------------------------------------------------------------------------
// LN2: out = LN(f0 + f1 + f2 + f3 + b2 + x)
// ---------------------------------------------------------------------------
__global__ __launch_bounds__(256) void ln2_kernel(
    const float* __restrict__ f0, const u16* __restrict__ f1,
    const u16* __restrict__ f2, const u16* __restrict__ f3,
    const float* __restrict__ b2, const float* __restrict__ bsrc,
    const float* __restrict__ g, const float* __restrict__ be,
    float* __restrict__ of)
{
  const int row = blockIdx.x * 4 + (threadIdx.x >> 6);
  const int lane = threadIdx.x & 63;
  const size_t base = (size_t)row * 512 + lane * 8;
  const int cb = lane * 8;
  float v[8];
#pragma unroll
  for (int t = 0; t < 8; ++t)
    v[t] = f0[base + t] + bf2f(f1[base + t]) + bf2f(f2[base + t]) + bf2f(f3[base + t])
         + b2[cb + t] + bsrc[base + t];
  float s = 0.f;
#pragma unroll
  for (int t = 0; t < 8; ++t) s += v[t];
#pragma unroll
  for (int off = 1; off < 64; off <<= 1) s += __shfl_xor(s, off, 64);
  const float mu = s * (1.0f / 512.0f);
  float qv = 0.f;
#pragma unroll
  for (int t = 0; t < 8; ++t) { float d = v[t] - mu; qv += d * d; }
#pragma unroll
  for (int off = 1; off < 64; off <<= 1) qv += __shfl_xor(qv, off, 64);
  const float rs = rsqrtf(qv * (1.0f / 512.0f) + 1e-5f);
#pragma unroll
  for (int t = 0; t < 8; ++t) {
    float xv = (v[t] - mu) * rs * g[cb + t] + be[cb + t];
    of[base + t] = xv;
  }
}

// ---------------------------------------------------------------------------
// prep kernels
// ---------------------------------------------------------------------------
__global__ __launch_bounds__(256) void cast_bf_kernel(
    const float* __restrict__ in, u16* __restrict__ out)
{
  const size_t i = ((size_t)blockIdx.x * 256 + threadIdx.x) * 8;
#pragma unroll
  for (int t = 0; t < 8; ++t) out[i + t] = f2bf(in[i + t]);
}

// Tiled transpose for the three 512x512 QKV weights in one launch (z = which).
__global__ __launch_bounds__(256) void transpose_qkv_kernel(
    const float* __restrict__ Wq, const float* __restrict__ Wk,
    const float* __restrict__ Wv, u16* __restrict__ dst)
{
  __shared__ u16 tile[32][33];
  const float* src = (blockIdx.z == 0) ? Wq : (blockIdx.z == 1) ? Wk : Wv;
  u16* d = dst + (size_t)blockIdx.z * 512 * 512;
  const int tx = threadIdx.x & 31, ty = threadIdx.x >> 5;
  const int n0 = blockIdx.x * 32, k0 = blockIdx.y * 32;
#pragma unroll
  for (int i = 0; i < 32; i += 8)
    tile[ty + i][tx] = f2bf(src[(size_t)(k0 + ty + i) * 512 + n0 + tx]);
  __syncthreads();
#pragma unroll
  for (int i = 0; i < 32; i += 8)
    d[(size_t)(n0 + ty + i) * 512 + k0 + tx] = tile[tx][ty + i];
}

__global__ __launch_bounds__(256) void transpose_bf_kernel(
    const float* __restrict__ src, u16* __restrict__ dst, int K, int N)
{
  __shared__ u16 tile[32][33];
  const int tx = threadIdx.x & 31, ty = threadIdx.x >> 5;
  const int n0 = blockIdx.x * 32, k0 = blockIdx.y * 32;
#pragma unroll
  for (int i = 0; i < 32; i += 8)
    tile[ty + i][tx] = f2bf(src[(size_t)(k0 + ty + i) * N + n0 + tx]);
  __syncthreads();
#pragma unroll
  for (int i = 0; i < 32; i += 8)
    dst[(size_t)(n0 + ty + i) * K + k0 + tx] = tile[tx][ty + i];
}

// ---------------------------------------------------------------------------
// launch
// ---------------------------------------------------------------------------
extern "C" void kernel_launch(void* const* d_in, const int* in_sizes, int n_in,
                              void* d_out, int out_size, void* d_ws, size_t ws_size,
                              hipStream_t stream) {
  const float* tokens = (const float*)d_in[0];
  const float* Wq = (const float*)d_in[1];
  const float* bq = (const float*)d_in[2];
  const float* Wk = (const float*)d_in[3];
  const float* bk = (const float*)d_in[4];
  const float* Wv = (const float*)d_in[5];
  const float* bv = (const float*)d_in[6];
  const float* dscale = (const float*)d_in[7];
  const float* W1 = (const float*)d_in[8];
  const float* b1 = (const float*)d_in[9];
  const float* W2 = (const float*)d_in[10];
  const float* b2 = (const float*)d_in[11];
  const float* g1 = (const float*)d_in[12];
  const float* be1 = (const float*)d_in[13];
  const float* g2 = (const float*)d_in[14];
  const float* be2 = (const float*)d_in[15];
  float* out = (float*)d_out;

  // Flat workspace layout (ws_size = 256 MiB). NO overlays.
  char* ws = (char*)d_ws;
  u16*   tok_bf = (u16*)(ws + 0);            //   8.4 MB
  u16*   wqkvT  = (u16*)(ws + 8388608);      //   1.6 MB
  u16*   w1T    = (u16*)(ws + 9961472);      //   2.1 MB
  u16*   w2T    = (u16*)(ws + 12058624);     //   2.1 MB
  u16*   qbuf   = (u16*)(ws + 14155776);     //   8.4 MB
  u16*   kbuf   = (u16*)(ws + 22544384);     //   8.4 MB
  u16*   vtbuf  = (u16*)(ws + 30932992);     //   8.4 MB
  u16*   Pbuf   = (u16*)(ws + 39321600);     //  64   MB (2 batches)
  float* y0buf  = (float*)(ws + 106430464);  //  16.8 MB
  u16*   y1buf  = (u16*)(ws + 123207680);    //   8.4 MB
  u16*   y2buf  = (u16*)(ws + 131596288);    //   8.4 MB
  u16*   y3buf  = (u16*)(ws + 139984896);    //   8.4 MB
  float* xf     = (float*)(ws + 148373504);  //  16.8 MB
  u16*   xbf    = (u16*)(ws + 165150720);    //   8.4 MB
  u16*   hbuf   = (u16*)(ws + 173539328);    //  33.6 MB
  float* f0buf  = (float*)(ws + 207093760);  //  16.8 MB
  u16*   f1buf  = (u16*)(ws + 223870976);    //   8.4 MB
  u16*   f2buf  = (u16*)(ws + 232259584);    //   8.4 MB
  u16*   f3buf  = (u16*)(ws + 240648192);    //   8.4 MB
  float* lbuf   = (float*)(ws + 249036800);  //  32 KB (ends 249069568 < 256 MiB)

  (void)hipMemsetAsync(lbuf, 0, 2 * 4096 * sizeof(float), stream);
  // y1/y2/y3 and f1/f2/f3 need no memset: readers only touch rows that
  // their producer GEMMs are guaranteed to have written.

  cast_bf_kernel<<<2048, 256, 0, stream>>>(tokens, tok_bf);
  transpose_qkv_kernel<<<dim3(16, 16, 3), 256, 0, stream>>>(Wq, Wk, Wv, wqkvT);
  transpose_bf_kernel<<<dim3(64, 16), 256, 0, stream>>>(W1, w1T, 512, 2048);
  transpose_bf_kernel<<<dim3(16, 64), 256, 0, stream>>>(W2, w2T, 2048, 512);

  gemm_qkv<<<192, 512, 131072, stream>>>(tok_bf, wqkvT, bq, bk, bv, qbuf, kbuf, vtbuf);

  // attention: 256-row tiles
  gemm_qk_p<<<dim3(136, 2), 512, 131072, stream>>>(qbuf, kbuf, dscale, Pbuf, lbuf);
  gemm_pv<<<160, 512, 131072, stream>>>(Pbuf, vtbuf, y0buf, y1buf, y2buf, y3buf);

  ln1_kernel<<<2048, 256, 0, stream>>>(y0buf, y1buf, y2buf, y3buf, lbuf, tokens,
                                       g1, be1, xf, xbf);

  gemm_ffn1<<<256, 512, 131072, stream>>>(xbf, w1T, b1, hbuf);

  gemm_ffn2<<<256, 512, 131072, stream>>>(hbuf, w2T, f0buf, f1buf, f2buf, f3buf);

  ln2_kernel<<<2048, 256, 0, stream>>>(f0buf, f1buf, f2buf, f3buf, b2, xf, g2, be2, out);
}

// Round 5
// 308.888 us; speedup vs baseline: 1.1405x; 1.1405x over previous
//
#include <hip/hip_runtime.h>
#include <hip/hip_bf16.h>
#include <math.h>

typedef unsigned short u16;
typedef __attribute__((ext_vector_type(8))) short short8;
typedef __attribute__((ext_vector_type(4))) float float4v;

#define MFMA_BF16(a, b, c) __builtin_amdgcn_mfma_f32_16x16x32_bf16((a), (b), (c), 0, 0, 0)

typedef const __attribute__((address_space(1))) void* gas_ptr;
typedef __attribute__((address_space(3))) void* las_ptr;

__device__ __forceinline__ u16 f2bf(float f) {
  __hip_bfloat16 h = __float2bfloat16(f);
  return __builtin_bit_cast(u16, h);
}

__device__ __forceinline__ float bf2f(u16 v) {
  return __builtin_bit_cast(float, (unsigned)v << 16);
}

__device__ __forceinline__ void load_lds16(const u16* g, u16* l) {
  __builtin_amdgcn_global_load_lds((gas_ptr)g, (las_ptr)l, 16, 0, 0);
}

// XCD-aware chunked block swizzle (T1). Bijective when nwg % 8 == 0.
// A/B measured (R1 vs R2): helps qkv/pv/ffn1/ffn2, HURTS gemm_qk_p.
__device__ __forceinline__ int xcd_swz(int bid, int nwg) {
  return (bid & 7) * (nwg >> 3) + (bid >> 3);
}

// ---------------------------------------------------------------------------
// 128x128 tile mainloop with double-buffered LDS and COUNTED vmcnt (T4):
//   per iter: vmcnt(4)+barrier -> ds_read+MFMA(buf t&1)
//             -> lgkmcnt(0)+barrier -> stage(t+2) into buf (t&1)
// Each thread issues exactly 4 global_load_lds per K-tile, so vmcnt(4)
// certifies tile t resident while tile t+1 stays in flight (never a full
// drain in steady state -- the R4 lesson). lgkmcnt(0) before the second
// barrier guarantees all ds_reads of the buffer completed before any
// wave's overwriting DMA can issue. LDS = 32KB -> 5 blocks/CU.
// ---------------------------------------------------------------------------
__device__ __forceinline__ void gemm_mainloop(
    const u16* __restrict__ A, const u16* __restrict__ Bt,
    int kb, int kend, int lda, int ldb,
    int m0, int n0, u16* As, u16* Bs, float4v acc[4][4])
{
  const int tid = threadIdx.x;
  const int w = tid >> 6, lane = tid & 63;
  const int wr = w >> 1, wc = w & 1;
  const int lr = lane & 15, lk = (lane >> 4) * 8;

  auto stage = [&](int buf, int k0) {
#pragma unroll
    for (int c = 0; c < 2; ++c) {
      int idx = c * 256 + w * 64 + lane;
      int r = idx >> 2, c8 = idx & 3;
      load_lds16(A + (size_t)(m0 + r) * lda + k0 + c8 * 8,
                 As + buf * 4096 + (size_t)(c * 256 + w * 64) * 8);
      load_lds16(Bt + (size_t)(n0 + r) * ldb + k0 + c8 * 8,
                 Bs + buf * 4096 + (size_t)(c * 256 + w * 64) * 8);
    }
  };

  const int nt = (kend - kb) >> 5;
  stage(0, kb);
  if (nt > 1) stage(1, kb + 32);
  for (int t = 0; t < nt; ++t) {
    // certify tile t resident; keep tile t+1's loads in flight
    if (t + 1 < nt) asm volatile("s_waitcnt vmcnt(4)\n\ts_barrier" ::: "memory");
    else            asm volatile("s_waitcnt vmcnt(0)\n\ts_barrier" ::: "memory");
    const u16* Ab = As + (t & 1) * 4096;
    const u16* Bb = Bs + (t & 1) * 4096;
    short8 af[4], bf[4];
#pragma unroll
    for (int mt = 0; mt < 4; ++mt)
      af[mt] = *(const short8*)&Ab[(wr * 64 + mt * 16 + lr) * 32 + lk];
#pragma unroll
    for (int nt2 = 0; nt2 < 4; ++nt2)
      bf[nt2] = *(const short8*)&Bb[(wc * 64 + nt2 * 16 + lr) * 32 + lk];
#pragma unroll
    for (int mt = 0; mt < 4; ++mt)
#pragma unroll
      for (int nt2 = 0; nt2 < 4; ++nt2)
        acc[mt][nt2] = MFMA_BF16(af[mt], bf[nt2], acc[mt][nt2]);
    if (t + 2 < nt) {
      // all my LDS reads done, then sync, then safe to overwrite buf (t&1)
      asm volatile("s_waitcnt lgkmcnt(0)\n\ts_barrier" ::: "memory");
      stage(t & 1, kb + (t + 2) * 32);
    }
  }
}

// ---------------------------------------------------------------------------
// GEMM 1: QKV projection. Grid (12,64) flattened+swizzled. V is written
// ROW-major (coalesced like Q/K); transpose_v_kernel produces V^T after.
// (Old epilogue wrote V^T directly = 2B/lane stride-8KB scatter.)
// ---------------------------------------------------------------------------
__global__ __launch_bounds__(256) void gemm_qkv(
    const u16* __restrict__ A, const u16* __restrict__ Bt,
    const float* __restrict__ bq, const float* __restrict__ bk, const float* __restrict__ bv,
    u16* __restrict__ qo, u16* __restrict__ ko, u16* __restrict__ vo)
{
  __shared__ u16 As[2 * 128 * 32], Bs[2 * 128 * 32];
  float4v acc[4][4];
#pragma unroll
  for (int mt = 0; mt < 4; ++mt)
#pragma unroll
    for (int nt = 0; nt < 4; ++nt) acc[mt][nt] = (float4v){0.f, 0.f, 0.f, 0.f};
  const int s = xcd_swz(blockIdx.x + 12 * blockIdx.y, 12 * 64);
  const int m0 = (s / 12) * 128, n0 = (s % 12) * 128;
  gemm_mainloop(A, Bt, 0, 512, 512, 512, m0, n0, As, Bs, acc);
  const int tid = threadIdx.x, w = tid >> 6, lane = tid & 63;
  const int wr = w >> 1, wc = w & 1, lr = lane & 15, lg = lane >> 4;
#pragma unroll
  for (int mt = 0; mt < 4; ++mt) {
#pragma unroll
    for (int nt = 0; nt < 4; ++nt) {
      int n = n0 + wc * 64 + nt * 16 + lr;
#pragma unroll
      for (int r = 0; r < 4; ++r) {
        int i = m0 + wr * 64 + mt * 16 + lg * 4 + r;
        float v = acc[mt][nt][r];
        if (n < 512) {
          qo[(size_t)i * 512 + n] = f2bf(v + bq[n]);
        } else if (n < 1024) {
          ko[(size_t)i * 512 + (n - 512)] = f2bf(v + bk[n - 512]);
        } else {
          vo[(size_t)i * 512 + (n - 1024)] = f2bf(v + bv[n - 1024]);
        }
      }
    }
  }
}

// ---------------------------------------------------------------------------
// V transpose: [2][4096][512] -> [2][512][4096], 32x32 tiles.
// ---------------------------------------------------------------------------
__global__ __launch_bounds__(256) void transpose_v_kernel(
    const u16* __restrict__ src, u16* __restrict__ dst)
{
  __shared__ u16 tile[32][33];
  const int b = blockIdx.z;
  const int t0 = blockIdx.x * 32, d0 = blockIdx.y * 32;
  const u16* sp = src + (size_t)b * 4096 * 512;
  u16* dp = dst + (size_t)b * 512 * 4096;
  const int tx = threadIdx.x & 31, ty = threadIdx.x >> 5;
#pragma unroll
  for (int i = 0; i < 32; i += 8)
    tile[ty + i][tx] = sp[(size_t)(t0 + ty + i) * 512 + d0 + tx];
  __syncthreads();
#pragma unroll
  for (int i = 0; i < 32; i += 8)
    dp[(size_t)(d0 + ty + i) * 4096 + t0 + tx] = tile[tx][ty + i];
}

// ---------------------------------------------------------------------------
// Attention pass 1: P = exp(QK^T/sqrt(d) - ds*dist), causal, bf16 out.
// NO XCD swizzle (R2 A/B: it hurt here). Both batches per launch.
// ---------------------------------------------------------------------------
__global__ __launch_bounds__(256) void gemm_qk_p(
    const u16* __restrict__ q, const u16* __restrict__ k,
    const float* __restrict__ dsp,
    u16* __restrict__ P, float* __restrict__ l)
{
  __shared__ u16 As[2 * 128 * 32], Bs[2 * 128 * 32];
  float4v acc[4][4];
#pragma unroll
  for (int mt = 0; mt < 4; ++mt)
#pragma unroll
    for (int nt = 0; nt < 4; ++nt) acc[mt][nt] = (float4v){0.f, 0.f, 0.f, 0.f};
  const int b = blockIdx.y;
  const u16* qb = q + (size_t)b * 4096 * 512;
  const u16* kb = k + (size_t)b * 4096 * 512;
  u16* Pb = P + (size_t)b * 4096 * 4096;
  float* lb = l + b * 4096;
  int idx = blockIdx.x;
  int tm = (int)((sqrtf(8.0f * (float)idx + 1.0f) - 1.0f) * 0.5f);
  while ((tm + 1) * (tm + 2) / 2 <= idx) ++tm;
  while (tm * (tm + 1) / 2 > idx) --tm;
  int tn = idx - tm * (tm + 1) / 2;
  const int m0 = tm * 128, n0 = tn * 128;
  gemm_mainloop(qb, kb, 0, 512, 512, 512, m0, n0, As, Bs, acc);
  const int tid = threadIdx.x, w = tid >> 6, lane = tid & 63;
  const int wr = w >> 1, wc = w & 1, lr = lane & 15, lg = lane >> 4;
  const float invs = 0.04419417382415922f;   // 1/sqrt(512)
  const float dsi = dsp[0] * invs;
  const float L2E = 1.4426950408889634f;
  float rs[4][4];
#pragma unroll
  for (int mt = 0; mt < 4; ++mt)
#pragma unroll
    for (int r = 0; r < 4; ++r) rs[mt][r] = 0.f;
#pragma unroll
  for (int mt = 0; mt < 4; ++mt) {
#pragma unroll
    for (int nt = 0; nt < 4; ++nt) {
      int j = n0 + wc * 64 + nt * 16 + lr;
#pragma unroll
      for (int r = 0; r < 4; ++r) {
        int i = m0 + wr * 64 + mt * 16 + lg * 4 + r;
        float x = acc[mt][nt][r] * invs - dsi * fabsf((float)(i - j));
        float p = (j > i) ? 0.f : exp2f(x * L2E);
        Pb[(size_t)i * 4096 + j] = f2bf(p);
        rs[mt][r] += p;
      }
    }
  }
#pragma unroll
  for (int mt = 0; mt < 4; ++mt) {
#pragma unroll
    for (int r = 0; r < 4; ++r) {
      float v = rs[mt][r];
#pragma unroll
      for (int off = 1; off < 16; off <<= 1) v += __shfl_xor(v, off, 64);
      if (lr == 0)
        atomicAdd(&lb[m0 + wr * 64 + mt * 16 + lg * 4 + r], v);
    }
  }
}

// ---------------------------------------------------------------------------
// Attention pass 2: P @ V with K-chunks of <=1024 elems (<=32 iters).
// chunks per tm = (tm>>3)+1 (max 4), total (tm,chunk) pairs = 80.
// Grid (4, 80, 2) flattened+swizzled over 640. NO atomics:
//   chunk 0 -> y0 fp32; 1/2/3 -> y1/y2/y3 bf16 (valid rows>=1024/2048/3072;
//   ln1 reads conditionally, no memset).
// ---------------------------------------------------------------------------
__global__ __launch_bounds__(256) void gemm_pv(
    const u16* __restrict__ P, const u16* __restrict__ vt,
    float* __restrict__ y0, u16* __restrict__ y1,
    u16* __restrict__ y2, u16* __restrict__ y3)
{
  __shared__ u16 As[2 * 128 * 32], Bs[2 * 128 * 32];
  float4v acc[4][4];
#pragma unroll
  for (int mt = 0; mt < 4; ++mt)
#pragma unroll
    for (int nt = 0; nt < 4; ++nt) acc[mt][nt] = (float4v){0.f, 0.f, 0.f, 0.f};
  const int s = xcd_swz(blockIdx.x + 4 * (blockIdx.y + 80 * blockIdx.z), 640);
  const int b = s / 320;
  const int t2 = s % 320;
  const int xb = t2 % 4;
  int rem = t2 / 4;
  const u16* Pb = P + (size_t)b * 4096 * 4096;
  const u16* vb = vt + (size_t)b * 512 * 4096;
  int tm = 0, cpt = 1;
  while (rem >= cpt) { rem -= cpt; ++tm; cpt = (tm >> 3) + 1; }
  const int m0 = tm * 128, n0 = xb * 128;
  const int kb = rem * 1024;
  const int kfull = (tm + 1) * 128;
  const int kend = (kb + 1024 < kfull) ? (kb + 1024) : kfull;
  gemm_mainloop(Pb, vb, kb, kend, 4096, 4096, m0, n0, As, Bs, acc);
  const int tid = threadIdx.x, w = tid >> 6, lane = tid & 63;
  const int wr = w >> 1, wc = w & 1, lr = lane & 15, lg = lane >> 4;
  const size_t bofs = (size_t)b * 4096 * 512;
#pragma unroll
  for (int mt = 0; mt < 4; ++mt) {
#pragma unroll
    for (int nt = 0; nt < 4; ++nt) {
      int n = n0 + wc * 64 + nt * 16 + lr;
#pragma unroll
      for (int r = 0; r < 4; ++r) {
        int i = m0 + wr * 64 + mt * 16 + lg * 4 + r;
        size_t o = bofs + (size_t)i * 512 + n;
        float v = acc[mt][nt][r];
        if (rem == 0)      y0[o] = v;
        else if (rem == 1) y1[o] = f2bf(v);
        else if (rem == 2) y2[o] = f2bf(v);
        else               y3[o] = f2bf(v);
      }
    }
  }
}

// ---------------------------------------------------------------------------
// GEMM: FFN1 (relu epilogue). Grid (16,64) flattened+swizzled.
// ---------------------------------------------------------------------------
__global__ __launch_bounds__(256) void gemm_ffn1(
    const u16* __restrict__ A, const u16* __restrict__ Bt,
    const float* __restrict__ b1, u16* __restrict__ h)
{
  __shared__ u16 As[2 * 128 * 32], Bs[2 * 128 * 32];
  float4v acc[4][4];
#pragma unroll
  for (int mt = 0; mt < 4; ++mt)
#pragma unroll
    for (int nt = 0; nt < 4; ++nt) acc[mt][nt] = (float4v){0.f, 0.f, 0.f, 0.f};
  const int s = xcd_swz(blockIdx.x + 16 * blockIdx.y, 16 * 64);
  const int m0 = (s / 16) * 128, n0 = (s % 16) * 128;
  gemm_mainloop(A, Bt, 0, 512, 512, 512, m0, n0, As, Bs, acc);
  const int tid = threadIdx.x, w = tid >> 6, lane = tid & 63;
  const int wr = w >> 1, wc = w & 1, lr = lane & 15, lg = lane >> 4;
#pragma unroll
  for (int mt = 0; mt < 4; ++mt) {
#pragma unroll
    for (int nt = 0; nt < 4; ++nt) {
      int n = n0 + wc * 64 + nt * 16 + lr;
#pragma unroll
      for (int r = 0; r < 4; ++r) {
        int i = m0 + wr * 64 + mt * 16 + lg * 4 + r;
        h[(size_t)i * 2048 + n] = f2bf(fmaxf(acc[mt][nt][r] + b1[n], 0.f));
      }
    }
  }
}

// ---------------------------------------------------------------------------
// GEMM: FFN2, K=2048 split x2 (32 iters/block), NO atomics:
//   z=0 -> fp32 store to f0 ; z=1 -> bf16 store to f1. LN2 sums.
// Grid (4,64,2) flattened+swizzled over 512.
// ---------------------------------------------------------------------------
__global__ __launch_bounds__(256) void gemm_ffn2(
    const u16* __restrict__ A, const u16* __restrict__ Bt,
    float* __restrict__ f0, u16* __restrict__ f1)
{
  __shared__ u16 As[2 * 128 * 32], Bs[2 * 128 * 32];
  float4v acc[4][4];
#pragma unroll
  for (int mt = 0; mt < 4; ++mt)
#pragma unroll
    for (int nt = 0; nt < 4; ++nt) acc[mt][nt] = (float4v){0.f, 0.f, 0.f, 0.f};
  const int s = xcd_swz(blockIdx.x + 4 * (blockIdx.y + 64 * blockIdx.z), 512);
  const int zz = s / 256;
  const int t2 = s % 256;
  const int m0 = (t2 / 4) * 128, n0 = (t2 % 4) * 128;
  const int kb = zz * 1024;
  gemm_mainloop(A, Bt, kb, kb + 1024, 2048, 2048, m0, n0, As, Bs, acc);
  const int tid = threadIdx.x, w = tid >> 6, lane = tid & 63;
  const int wr = w >> 1, wc = w & 1, lr = lane & 15, lg = lane >> 4;
#pragma unroll
  for (int mt = 0; mt < 4; ++mt) {
#pragma unroll
    for (int nt = 0; nt < 4; ++nt) {
      int n = n0 + wc * 64 + nt * 16 + lr;
#pragma unroll
      for (int r = 0; r < 4; ++r) {
        int i = m0 + wr * 64 + mt * 16 + lg * 4 + r;
        if (zz == 0) f0[(size_t)i * 512 + n] = acc[mt][nt][r];
        else         f1[(size_t)i * 512 + n] = f2bf(acc[mt][nt][r]);
      }
    }
  }
}

// ---------------------------------------------------------------------------
// LN1: x = LN((y0 [+y1 +y2 +y3 row-conditional])/l + tokens); fp32+bf16 out.
// ---------------------------------------------------------------------------
__global__ __launch_bounds__(256) void ln1_kernel(
    const float* __restrict__ y0, const u16* __restrict__ y1,
    const u16* __restrict__ y2, const u16* __restrict__ y3,
    const float* __restrict__ lsum, const float* __restrict__ tok,
    const float* __restrict__ g, const float* __restrict__ be,
    float* __restrict__ of, u16* __restrict__ ob)
{
  const int row = blockIdx.x * 4 + (threadIdx.x >> 6);
  const int lane = threadIdx.x & 63;
  const int rloc = row & 4095;  // row within batch
  const size_t base = (size_t)row * 512 + lane * 8;
  const float linv = 1.0f / lsum[row];
  float v[8];
#pragma unroll
  for (int t = 0; t < 8; ++t) v[t] = y0[base + t];
  if (rloc >= 1024) {
#pragma unroll
    for (int t = 0; t < 8; ++t) v[t] += bf2f(y1[base + t]);
  }
  if (rloc >= 2048) {
#pragma unroll
    for (int t = 0; t < 8; ++t) v[t] += bf2f(y2[base + t]);
  }
  if (rloc >= 3072) {
#pragma unroll
    for (int t = 0; t < 8; ++t) v[t] += bf2f(y3[base + t]);
  }
#pragma unroll
  for (int t = 0; t < 8; ++t) v[t] = v[t] * linv + tok[base + t];
  float s = 0.f;
#pragma unroll
  for (int t = 0; t < 8; ++t) s += v[t];
#pragma unroll
  for (int off = 1; off < 64; off <<= 1) s += __shfl_xor(s, off, 64);
  const float mu = s * (1.0f / 512.0f);
  float qv = 0.f;
#pragma unroll
  for (int t = 0; t < 8; ++t) { float d = v[t] - mu; qv += d * d; }
#pragma unroll
  for (int off = 1; off < 64; off <<= 1) qv += __shfl_xor(qv, off, 64);
  const float rs = rsqrtf(qv * (1.0f / 512.0f) + 1e-5f);
  const int cb = lane * 8;
#pragma unroll
  for (int t = 0; t < 8; ++t) {
    float xv = (v[t] - mu) * rs * g[cb + t] + be[cb + t];
    of[base + t] = xv;
    ob[base + t] = f2bf(xv);
  }
}

// ---------------------------------------------------------------------------
// LN2: out = LN(f0 + f1 + b2 + x)
// ---------------------------------------------------------------------------
__global__ __launch_bounds__(256) void ln2_kernel(
    const float* __restrict__ f0, const u16* __restrict__ f1,
    const float* __restrict__ b2, const float* __restrict__ bsrc,
    const float* __restrict__ g, const float* __restrict__ be,
    float* __restrict__ of)
{
  const int row = blockIdx.x * 4 + (threadIdx.x >> 6);
  const int lane = threadIdx.x & 63;
  const size_t base = (size_t)row * 512 + lane * 8;
  const int cb = lane * 8;
  float v[8];
#pragma unroll
  for (int t = 0; t < 8; ++t)
    v[t] = f0[base + t] + bf2f(f1[base + t]) + b2[cb + t] + bsrc[base + t];
  float s = 0.f;
#pragma unroll
  for (int t = 0; t < 8; ++t) s += v[t];
#pragma unroll
  for (int off = 1; off < 64; off <<= 1) s += __shfl_xor(s, off, 64);
  const float mu = s * (1.0f / 512.0f);
  float qv = 0.f;
#pragma unroll
  for (int t = 0; t < 8; ++t) { float d = v[t] - mu; qv += d * d; }
#pragma unroll
  for (int off = 1; off < 64; off <<= 1) qv += __shfl_xor(qv, off, 64);
  const float rs = rsqrtf(qv * (1.0f / 512.0f) + 1e-5f);
#pragma unroll
  for (int t = 0; t < 8; ++t) {
    float xv = (v[t] - mu) * rs * g[cb + t] + be[cb + t];
    of[base + t] = xv;
  }
}

// ---------------------------------------------------------------------------
// prep kernels
// ---------------------------------------------------------------------------
__global__ __launch_bounds__(256) void cast_bf_kernel(
    const float* __restrict__ in, u16* __restrict__ out)
{
  const size_t i = ((size_t)blockIdx.x * 256 + threadIdx.x) * 8;
#pragma unroll
  for (int t = 0; t < 8; ++t) out[i + t] = f2bf(in[i + t]);
}

// Tiled transpose for the three 512x512 QKV weights in one launch (z = which).
__global__ __launch_bounds__(256) void transpose_qkv_kernel(
    const float* __restrict__ Wq, const float* __restrict__ Wk,
    const float* __restrict__ Wv, u16* __restrict__ dst)
{
  __shared__ u16 tile[32][33];
  const float* src = (blockIdx.z == 0) ? Wq : (blockIdx.z == 1) ? Wk : Wv;
  u16* d = dst + (size_t)blockIdx.z * 512 * 512;
  const int tx = threadIdx.x & 31, ty = threadIdx.x >> 5;
  const int n0 = blockIdx.x * 32, k0 = blockIdx.y * 32;
#pragma unroll
  for (int i = 0; i < 32; i += 8)
    tile[ty + i][tx] = f2bf(src[(size_t)(k0 + ty + i) * 512 + n0 + tx]);
  __syncthreads();
#pragma unroll
  for (int i = 0; i < 32; i += 8)
    d[(size_t)(n0 + ty + i) * 512 + k0 + tx] = tile[tx][ty + i];
}

__global__ __launch_bounds__(256) void transpose_bf_kernel(
    const float* __restrict__ src, u16* __restrict__ dst, int K, int N)
{
  __shared__ u16 tile[32][33];
  const int tx = threadIdx.x & 31, ty = threadIdx.x >> 5;
  const int n0 = blockIdx.x * 32, k0 = blockIdx.y * 32;
#pragma unroll
  for (int i = 0; i < 32; i += 8)
    tile[ty + i][tx] = f2bf(src[(size_t)(k0 + ty + i) * N + n0 + tx]);
  __syncthreads();
#pragma unroll
  for (int i = 0; i < 32; i += 8)
    dst[(size_t)(n0 + ty + i) * K + k0 + tx] = tile[tx][ty + i];
}

// ---------------------------------------------------------------------------
// launch
// ---------------------------------------------------------------------------
extern "C" void kernel_launch(void* const* d_in, const int* in_sizes, int n_in,
                              void* d_out, int out_size, void* d_ws, size_t ws_size,
                              hipStream_t stream) {
  const float* tokens = (const float*)d_in[0];
  const float* Wq = (const float*)d_in[1];
  const float* bq = (const float*)d_in[2];
  const float* Wk = (const float*)d_in[3];
  const float* bk = (const float*)d_in[4];
  const float* Wv = (const float*)d_in[5];
  const float* bv = (const float*)d_in[6];
  const float* dscale = (const float*)d_in[7];
  const float* W1 = (const float*)d_in[8];
  const float* b1 = (const float*)d_in[9];
  const float* W2 = (const float*)d_in[10];
  const float* b2 = (const float*)d_in[11];
  const float* g1 = (const float*)d_in[12];
  const float* be1 = (const float*)d_in[13];
  const float* g2 = (const float*)d_in[14];
  const float* be2 = (const float*)d_in[15];
  float* out = (float*)d_out;

  // Flat workspace layout (ws_size = 256 MiB). NO overlays.
  char* ws = (char*)d_ws;
  u16*   tok_bf = (u16*)(ws + 0);            //   8.4 MB
  u16*   wqkvT  = (u16*)(ws + 8388608);      //   1.6 MB
  u16*   w1T    = (u16*)(ws + 9961472);      //   2.1 MB
  u16*   w2T    = (u16*)(ws + 12058624);     //   2.1 MB
  u16*   qbuf   = (u16*)(ws + 14155776);     //   8.4 MB
  u16*   kbuf   = (u16*)(ws + 22544384);     //   8.4 MB
  u16*   vtbuf  = (u16*)(ws + 30932992);     //   8.4 MB
  u16*   Pbuf   = (u16*)(ws + 39321600);     //  64   MB (2 batches)
  float* y0buf  = (float*)(ws + 106430464);  //  16.8 MB
  u16*   y1buf  = (u16*)(ws + 123207680);    //   8.4 MB
  u16*   y2buf  = (u16*)(ws + 131596288);    //   8.4 MB
  u16*   y3buf  = (u16*)(ws + 139984896);    //   8.4 MB
  float* xf     = (float*)(ws + 148373504);  //  16.8 MB
  u16*   xbf    = (u16*)(ws + 165150720);    //   8.4 MB
  u16*   hbuf   = (u16*)(ws + 173539328);    //  33.6 MB
  float* f0buf  = (float*)(ws + 207093760);  //  16.8 MB
  u16*   f1buf  = (u16*)(ws + 223870976);    //   8.4 MB
  float* lbuf   = (float*)(ws + 232259584);  //  32 KB (ends 232292352)
  u16*   vbuf   = (u16*)(ws + 232292352);    //   8.4 MB (ends 240680960 < 256 MiB)

  (void)hipMemsetAsync(lbuf, 0, 2 * 4096 * sizeof(float), stream);
  // y1/y2/y3 need no memset: ln1 reads them only for rows gemm_pv wrote.

  cast_bf_kernel<<<2048, 256, 0, stream>>>(tokens, tok_bf);
  transpose_qkv_kernel<<<dim3(16, 16, 3), 256, 0, stream>>>(Wq, Wk, Wv, wqkvT);
  transpose_bf_kernel<<<dim3(64, 16), 256, 0, stream>>>(W1, w1T, 512, 2048);
  transpose_bf_kernel<<<dim3(16, 64), 256, 0, stream>>>(W2, w2T, 2048, 512);

  gemm_qkv<<<dim3(12, 64), 256, 0, stream>>>(tok_bf, wqkvT, bq, bk, bv, qbuf, kbuf, vbuf);
  transpose_v_kernel<<<dim3(128, 16, 2), 256, 0, stream>>>(vbuf, vtbuf);

  // attention: both batches per launch
  gemm_qk_p<<<dim3(528, 2), 256, 0, stream>>>(qbuf, kbuf, dscale, Pbuf, lbuf);
  gemm_pv<<<dim3(4, 80, 2), 256, 0, stream>>>(Pbuf, vtbuf, y0buf, y1buf, y2buf, y3buf);

  ln1_kernel<<<2048, 256, 0, stream>>>(y0buf, y1buf, y2buf, y3buf, lbuf, tokens,
                                       g1, be1, xf, xbf);

  gemm_ffn1<<<dim3(16, 64), 256, 0, stream>>>(xbf, w1T, b1, hbuf);

  gemm_ffn2<<<dim3(4, 64, 2), 256, 0, stream>>>(hbuf, w2T, f0buf, f1buf);

  ln2_kernel<<<2048, 256, 0, stream>>>(f0buf, f1buf, b2, xf, g2, be2, out);
}

// Round 6
// 297.266 us; speedup vs baseline: 1.1851x; 1.0391x over previous
//
#include <hip/hip_runtime.h>
#include <hip/hip_bf16.h>
#include <math.h>

typedef unsigned short u16;
typedef __attribute__((ext_vector_type(8))) short short8;
typedef __attribute__((ext_vector_type(4))) float float4v;

#define MFMA_BF16(a, b, c) __builtin_amdgcn_mfma_f32_16x16x32_bf16((a), (b), (c), 0, 0, 0)

typedef const __attribute__((address_space(1))) void* gas_ptr;
typedef __attribute__((address_space(3))) void* las_ptr;

__device__ __forceinline__ u16 f2bf(float f) {
  __hip_bfloat16 h = __float2bfloat16(f);
  return __builtin_bit_cast(u16, h);
}

__device__ __forceinline__ float bf2f(u16 v) {
  return __builtin_bit_cast(float, (unsigned)v << 16);
}

__device__ __forceinline__ void load_lds16(const u16* g, u16* l) {
  __builtin_amdgcn_global_load_lds((gas_ptr)g, (las_ptr)l, 16, 0, 0);
}

// XCD-aware chunked block swizzle (T1). Bijective when nwg % 8 == 0.
// A/B measured (R1 vs R2): helps qkv/pv/ffn1/ffn2, HURTS gemm_qk_p.
__device__ __forceinline__ int xcd_swz(int bid, int nwg) {
  return (bid & 7) * (nwg >> 3) + (bid >> 3);
}

// ---------------------------------------------------------------------------
// Single-buffer m97-style mainloop (R3 config) -- used by gemm_qk_p.
// Measured best for qk_p (49.4us): 16KB LDS -> ~6 blocks/CU; TLP covers
// the staging drain. Every pipelining variant regressed this kernel
// (R1 dbuf-drain0 +16us, R4 256^2 +19us, R5 counted-vmcnt +11us).
// ---------------------------------------------------------------------------
__device__ __forceinline__ void gemm_mainloop_sb(
    const u16* __restrict__ A, const u16* __restrict__ Bt,
    int kb, int kend, int lda, int ldb,
    int m0, int n0, u16* As, u16* Bs, float4v acc[4][4])
{
  const int tid = threadIdx.x;
  const int w = tid >> 6, lane = tid & 63;
  const int wr = w >> 1, wc = w & 1;
  const int lr = lane & 15, lk = (lane >> 4) * 8;
  for (int k0 = kb; k0 < kend; k0 += 32) {
#pragma unroll
    for (int c = 0; c < 2; ++c) {
      int idx = c * 256 + w * 64 + lane;
      int r = idx >> 2, c8 = idx & 3;
      load_lds16(A + (size_t)(m0 + r) * lda + k0 + c8 * 8, As + (size_t)(c * 256 + w * 64) * 8);
      load_lds16(Bt + (size_t)(n0 + r) * ldb + k0 + c8 * 8, Bs + (size_t)(c * 256 + w * 64) * 8);
    }
    __syncthreads();
    short8 af[4], bf[4];
#pragma unroll
    for (int mt = 0; mt < 4; ++mt)
      af[mt] = *(const short8*)&As[(wr * 64 + mt * 16 + lr) * 32 + lk];
#pragma unroll
    for (int nt = 0; nt < 4; ++nt)
      bf[nt] = *(const short8*)&Bs[(wc * 64 + nt * 16 + lr) * 32 + lk];
#pragma unroll
    for (int mt = 0; mt < 4; ++mt)
#pragma unroll
      for (int nt = 0; nt < 4; ++nt)
        acc[mt][nt] = MFMA_BF16(af[mt], bf[nt], acc[mt][nt]);
    __syncthreads();
  }
}

// ---------------------------------------------------------------------------
// Counted-vmcnt double-buffer mainloop (R5 config) -- used by the four
// swizzled GEMMs (bundle measured ~-12us vs single-buffer on them).
//   per iter: vmcnt(4)+barrier -> ds_read+MFMA(buf t&1)
//             -> lgkmcnt(0)+barrier -> stage(t+2) into buf (t&1)
// ---------------------------------------------------------------------------
__device__ __forceinline__ void gemm_mainloop_cnt(
    const u16* __restrict__ A, const u16* __restrict__ Bt,
    int kb, int kend, int lda, int ldb,
    int m0, int n0, u16* As, u16* Bs, float4v acc[4][4])
{
  const int tid = threadIdx.x;
  const int w = tid >> 6, lane = tid & 63;
  const int wr = w >> 1, wc = w & 1;
  const int lr = lane & 15, lk = (lane >> 4) * 8;

  auto stage = [&](int buf, int k0) {
#pragma unroll
    for (int c = 0; c < 2; ++c) {
      int idx = c * 256 + w * 64 + lane;
      int r = idx >> 2, c8 = idx & 3;
      load_lds16(A + (size_t)(m0 + r) * lda + k0 + c8 * 8,
                 As + buf * 4096 + (size_t)(c * 256 + w * 64) * 8);
      load_lds16(Bt + (size_t)(n0 + r) * ldb + k0 + c8 * 8,
                 Bs + buf * 4096 + (size_t)(c * 256 + w * 64) * 8);
    }
  };

  const int nt = (kend - kb) >> 5;
  stage(0, kb);
  if (nt > 1) stage(1, kb + 32);
  for (int t = 0; t < nt; ++t) {
    if (t + 1 < nt) asm volatile("s_waitcnt vmcnt(4)\n\ts_barrier" ::: "memory");
    else            asm volatile("s_waitcnt vmcnt(0)\n\ts_barrier" ::: "memory");
    const u16* Ab = As + (t & 1) * 4096;
    const u16* Bb = Bs + (t & 1) * 4096;
    short8 af[4], bf[4];
#pragma unroll
    for (int mt = 0; mt < 4; ++mt)
      af[mt] = *(const short8*)&Ab[(wr * 64 + mt * 16 + lr) * 32 + lk];
#pragma unroll
    for (int nt2 = 0; nt2 < 4; ++nt2)
      bf[nt2] = *(const short8*)&Bb[(wc * 64 + nt2 * 16 + lr) * 32 + lk];
#pragma unroll
    for (int mt = 0; mt < 4; ++mt)
#pragma unroll
      for (int nt2 = 0; nt2 < 4; ++nt2)
        acc[mt][nt2] = MFMA_BF16(af[mt], bf[nt2], acc[mt][nt2]);
    if (t + 2 < nt) {
      asm volatile("s_waitcnt lgkmcnt(0)\n\ts_barrier" ::: "memory");
      stage(t & 1, kb + (t + 2) * 32);
    }
  }
}

// ---------------------------------------------------------------------------
// GEMM 1: QKV projection. Grid (12,64) flattened+swizzled. V written
// ROW-major (coalesced); transpose_v_kernel produces V^T after.
// ---------------------------------------------------------------------------
__global__ __launch_bounds__(256) void gemm_qkv(
    const u16* __restrict__ A, const u16* __restrict__ Bt,
    const float* __restrict__ bq, const float* __restrict__ bk, const float* __restrict__ bv,
    u16* __restrict__ qo, u16* __restrict__ ko, u16* __restrict__ vo)
{
  __shared__ u16 As[2 * 128 * 32], Bs[2 * 128 * 32];
  float4v acc[4][4];
#pragma unroll
  for (int mt = 0; mt < 4; ++mt)
#pragma unroll
    for (int nt = 0; nt < 4; ++nt) acc[mt][nt] = (float4v){0.f, 0.f, 0.f, 0.f};
  const int s = xcd_swz(blockIdx.x + 12 * blockIdx.y, 12 * 64);
  const int m0 = (s / 12) * 128, n0 = (s % 12) * 128;
  gemm_mainloop_cnt(A, Bt, 0, 512, 512, 512, m0, n0, As, Bs, acc);
  const int tid = threadIdx.x, w = tid >> 6, lane = tid & 63;
  const int wr = w >> 1, wc = w & 1, lr = lane & 15, lg = lane >> 4;
#pragma unroll
  for (int mt = 0; mt < 4; ++mt) {
#pragma unroll
    for (int nt = 0; nt < 4; ++nt) {
      int n = n0 + wc * 64 + nt * 16 + lr;
#pragma unroll
      for (int r = 0; r < 4; ++r) {
        int i = m0 + wr * 64 + mt * 16 + lg * 4 + r;
        float v = acc[mt][nt][r];
        if (n < 512) {
          qo[(size_t)i * 512 + n] = f2bf(v + bq[n]);
        } else if (n < 1024) {
          ko[(size_t)i * 512 + (n - 512)] = f2bf(v + bk[n - 512]);
        } else {
          vo[(size_t)i * 512 + (n - 1024)] = f2bf(v + bv[n - 1024]);
        }
      }
    }
  }
}

// ---------------------------------------------------------------------------
// V transpose: [2][4096][512] -> [2][512][4096], 32x32 tiles.
// ---------------------------------------------------------------------------
__global__ __launch_bounds__(256) void transpose_v_kernel(
    const u16* __restrict__ src, u16* __restrict__ dst)
{
  __shared__ u16 tile[32][33];
  const int b = blockIdx.z;
  const int t0 = blockIdx.x * 32, d0 = blockIdx.y * 32;
  const u16* sp = src + (size_t)b * 4096 * 512;
  u16* dp = dst + (size_t)b * 512 * 4096;
  const int tx = threadIdx.x & 31, ty = threadIdx.x >> 5;
#pragma unroll
  for (int i = 0; i < 32; i += 8)
    tile[ty + i][tx] = sp[(size_t)(t0 + ty + i) * 512 + d0 + tx];
  __syncthreads();
#pragma unroll
  for (int i = 0; i < 32; i += 8)
    dp[(size_t)(d0 + ty + i) * 4096 + t0 + tx] = tile[tx][ty + i];
}

// ---------------------------------------------------------------------------
// Attention pass 1: P = exp(QK^T/sqrt(d) - ds*dist), causal, bf16 out.
// Single-buffer loop, NO XCD swizzle (both A/B-measured best for this
// kernel). Both batches per launch.
// ---------------------------------------------------------------------------
__global__ __launch_bounds__(256) void gemm_qk_p(
    const u16* __restrict__ q, const u16* __restrict__ k,
    const float* __restrict__ dsp,
    u16* __restrict__ P, float* __restrict__ l)
{
  __shared__ u16 As[128 * 32], Bs[128 * 32];
  float4v acc[4][4];
#pragma unroll
  for (int mt = 0; mt < 4; ++mt)
#pragma unroll
    for (int nt = 0; nt < 4; ++nt) acc[mt][nt] = (float4v){0.f, 0.f, 0.f, 0.f};
  const int b = blockIdx.y;
  const u16* qb = q + (size_t)b * 4096 * 512;
  const u16* kb = k + (size_t)b * 4096 * 512;
  u16* Pb = P + (size_t)b * 4096 * 4096;
  float* lb = l + b * 4096;
  int idx = blockIdx.x;
  int tm = (int)((sqrtf(8.0f * (float)idx + 1.0f) - 1.0f) * 0.5f);
  while ((tm + 1) * (tm + 2) / 2 <= idx) ++tm;
  while (tm * (tm + 1) / 2 > idx) --tm;
  int tn = idx - tm * (tm + 1) / 2;
  const int m0 = tm * 128, n0 = tn * 128;
  gemm_mainloop_sb(qb, kb, 0, 512, 512, 512, m0, n0, As, Bs, acc);
  const int tid = threadIdx.x, w = tid >> 6, lane = tid & 63;
  const int wr = w >> 1, wc = w & 1, lr = lane & 15, lg = lane >> 4;
  const float invs = 0.04419417382415922f;   // 1/sqrt(512)
  const float dsi = dsp[0] * invs;
  const float L2E = 1.4426950408889634f;
  float rs[4][4];
#pragma unroll
  for (int mt = 0; mt < 4; ++mt)
#pragma unroll
    for (int r = 0; r < 4; ++r) rs[mt][r] = 0.f;
#pragma unroll
  for (int mt = 0; mt < 4; ++mt) {
#pragma unroll
    for (int nt = 0; nt < 4; ++nt) {
      int j = n0 + wc * 64 + nt * 16 + lr;
#pragma unroll
      for (int r = 0; r < 4; ++r) {
        int i = m0 + wr * 64 + mt * 16 + lg * 4 + r;
        float x = acc[mt][nt][r] * invs - dsi * fabsf((float)(i - j));
        float p = (j > i) ? 0.f : exp2f(x * L2E);
        Pb[(size_t)i * 4096 + j] = f2bf(p);
        rs[mt][r] += p;
      }
    }
  }
#pragma unroll
  for (int mt = 0; mt < 4; ++mt) {
#pragma unroll
    for (int r = 0; r < 4; ++r) {
      float v = rs[mt][r];
#pragma unroll
      for (int off = 1; off < 16; off <<= 1) v += __shfl_xor(v, off, 64);
      if (lr == 0)
        atomicAdd(&lb[m0 + wr * 64 + mt * 16 + lg * 4 + r], v);
    }
  }
}

// ---------------------------------------------------------------------------
// Attention pass 2: P @ V with K-chunks of <=1024 elems (<=32 iters).
// chunks per tm = (tm>>3)+1 (max 4), total (tm,chunk) pairs = 80.
// Grid (4, 80, 2) flattened+swizzled over 640. NO atomics:
//   chunk 0 -> y0 fp32; 1/2/3 -> y1/y2/y3 bf16 (valid rows>=1024/2048/3072;
//   ln1 reads conditionally, no memset).
// ---------------------------------------------------------------------------
__global__ __launch_bounds__(256) void gemm_pv(
    const u16* __restrict__ P, const u16* __restrict__ vt,
    float* __restrict__ y0, u16* __restrict__ y1,
    u16* __restrict__ y2, u16* __restrict__ y3)
{
  __shared__ u16 As[2 * 128 * 32], Bs[2 * 128 * 32];
  float4v acc[4][4];
#pragma unroll
  for (int mt = 0; mt < 4; ++mt)
#pragma unroll
    for (int nt = 0; nt < 4; ++nt) acc[mt][nt] = (float4v){0.f, 0.f, 0.f, 0.f};
  const int s = xcd_swz(blockIdx.x + 4 * (blockIdx.y + 80 * blockIdx.z), 640);
  const int b = s / 320;
  const int t2 = s % 320;
  const int xb = t2 % 4;
  int rem = t2 / 4;
  const u16* Pb = P + (size_t)b * 4096 * 4096;
  const u16* vb = vt + (size_t)b * 512 * 4096;
  int tm = 0, cpt = 1;
  while (rem >= cpt) { rem -= cpt; ++tm; cpt = (tm >> 3) + 1; }
  const int m0 = tm * 128, n0 = xb * 128;
  const int kb = rem * 1024;
  const int kfull = (tm + 1) * 128;
  const int kend = (kb + 1024 < kfull) ? (kb + 1024) : kfull;
  gemm_mainloop_cnt(Pb, vb, kb, kend, 4096, 4096, m0, n0, As, Bs, acc);
  const int tid = threadIdx.x, w = tid >> 6, lane = tid & 63;
  const int wr = w >> 1, wc = w & 1, lr = lane & 15, lg = lane >> 4;
  const size_t bofs = (size_t)b * 4096 * 512;
#pragma unroll
  for (int mt = 0; mt < 4; ++mt) {
#pragma unroll
    for (int nt = 0; nt < 4; ++nt) {
      int n = n0 + wc * 64 + nt * 16 + lr;
#pragma unroll
      for (int r = 0; r < 4; ++r) {
        int i = m0 + wr * 64 + mt * 16 + lg * 4 + r;
        size_t o = bofs + (size_t)i * 512 + n;
        float v = acc[mt][nt][r];
        if (rem == 0)      y0[o] = v;
        else if (rem == 1) y1[o] = f2bf(v);
        else if (rem == 2) y2[o] = f2bf(v);
        else               y3[o] = f2bf(v);
      }
    }
  }
}

// ---------------------------------------------------------------------------
// GEMM: FFN1 (relu epilogue). Grid (16,64) flattened+swizzled.
// ---------------------------------------------------------------------------
__global__ __launch_bounds__(256) void gemm_ffn1(
    const u16* __restrict__ A, const u16* __restrict__ Bt,
    const float* __restrict__ b1, u16* __restrict__ h)
{
  __shared__ u16 As[2 * 128 * 32], Bs[2 * 128 * 32];
  float4v acc[4][4];
#pragma unroll
  for (int mt = 0; mt < 4; ++mt)
#pragma unroll
    for (int nt = 0; nt < 4; ++nt) acc[mt][nt] = (float4v){0.f, 0.f, 0.f, 0.f};
  const int s = xcd_swz(blockIdx.x + 16 * blockIdx.y, 16 * 64);
  const int m0 = (s / 16) * 128, n0 = (s % 16) * 128;
  gemm_mainloop_cnt(A, Bt, 0, 512, 512, 512, m0, n0, As, Bs, acc);
  const int tid = threadIdx.x, w = tid >> 6, lane = tid & 63;
  const int wr = w >> 1, wc = w & 1, lr = lane & 15, lg = lane >> 4;
#pragma unroll
  for (int mt = 0; mt < 4; ++mt) {
#pragma unroll
    for (int nt = 0; nt < 4; ++nt) {
      int n = n0 + wc * 64 + nt * 16 + lr;
#pragma unroll
      for (int r = 0; r < 4; ++r) {
        int i = m0 + wr * 64 + mt * 16 + lg * 4 + r;
        h[(size_t)i * 2048 + n] = f2bf(fmaxf(acc[mt][nt][r] + b1[n], 0.f));
      }
    }
  }
}

// ---------------------------------------------------------------------------
// GEMM: FFN2, K=2048 split x2 (32 iters/block), NO atomics:
//   z=0 -> fp32 store to f0 ; z=1 -> bf16 store to f1. LN2 sums.
// Grid (4,64,2) flattened+swizzled over 512.
// ---------------------------------------------------------------------------
__global__ __launch_bounds__(256) void gemm_ffn2(
    const u16* __restrict__ A, const u16* __restrict__ Bt,
    float* __restrict__ f0, u16* __restrict__ f1)
{
  __shared__ u16 As[2 * 128 * 32], Bs[2 * 128 * 32];
  float4v acc[4][4];
#pragma unroll
  for (int mt = 0; mt < 4; ++mt)
#pragma unroll
    for (int nt = 0; nt < 4; ++nt) acc[mt][nt] = (float4v){0.f, 0.f, 0.f, 0.f};
  const int s = xcd_swz(blockIdx.x + 4 * (blockIdx.y + 64 * blockIdx.z), 512);
  const int zz = s / 256;
  const int t2 = s % 256;
  const int m0 = (t2 / 4) * 128, n0 = (t2 % 4) * 128;
  const int kb = zz * 1024;
  gemm_mainloop_cnt(A, Bt, kb, kb + 1024, 2048, 2048, m0, n0, As, Bs, acc);
  const int tid = threadIdx.x, w = tid >> 6, lane = tid & 63;
  const int wr = w >> 1, wc = w & 1, lr = lane & 15, lg = lane >> 4;
#pragma unroll
  for (int mt = 0; mt < 4; ++mt) {
#pragma unroll
    for (int nt = 0; nt < 4; ++nt) {
      int n = n0 + wc * 64 + nt * 16 + lr;
#pragma unroll
      for (int r = 0; r < 4; ++r) {
        int i = m0 + wr * 64 + mt * 16 + lg * 4 + r;
        if (zz == 0) f0[(size_t)i * 512 + n] = acc[mt][nt][r];
        else         f1[(size_t)i * 512 + n] = f2bf(acc[mt][nt][r]);
      }
    }
  }
}

// ---------------------------------------------------------------------------
// LN1: x = LN((y0 [+y1 +y2 +y3 row-conditional])/l + tokens); fp32+bf16 out.
// ---------------------------------------------------------------------------
__global__ __launch_bounds__(256) void ln1_kernel(
    const float* __restrict__ y0, const u16* __restrict__ y1,
    const u16* __restrict__ y2, const u16* __restrict__ y3,
    const float* __restrict__ lsum, const float* __restrict__ tok,
    const float* __restrict__ g, const float* __restrict__ be,
    float* __restrict__ of, u16* __restrict__ ob)
{
  const int row = blockIdx.x * 4 + (threadIdx.x >> 6);
  const int lane = threadIdx.x & 63;
  const int rloc = row & 4095;  // row within batch
  const size_t base = (size_t)row * 512 + lane * 8;
  const float linv = 1.0f / lsum[row];
  float v[8];
#pragma unroll
  for (int t = 0; t < 8; ++t) v[t] = y0[base + t];
  if (rloc >= 1024) {
#pragma unroll
    for (int t = 0; t < 8; ++t) v[t] += bf2f(y1[base + t]);
  }
  if (rloc >= 2048) {
#pragma unroll
    for (int t = 0; t < 8; ++t) v[t] += bf2f(y2[base + t]);
  }
  if (rloc >= 3072) {
#pragma unroll
    for (int t = 0; t < 8; ++t) v[t] += bf2f(y3[base + t]);
  }
#pragma unroll
  for (int t = 0; t < 8; ++t) v[t] = v[t] * linv + tok[base + t];
  float s = 0.f;
#pragma unroll
  for (int t = 0; t < 8; ++t) s += v[t];
#pragma unroll
  for (int off = 1; off < 64; off <<= 1) s += __shfl_xor(s, off, 64);
  const float mu = s * (1.0f / 512.0f);
  float qv = 0.f;
#pragma unroll
  for (int t = 0; t < 8; ++t) { float d = v[t] - mu; qv += d * d; }
#pragma unroll
  for (int off = 1; off < 64; off <<= 1) qv += __shfl_xor(qv, off, 64);
  const float rs = rsqrtf(qv * (1.0f / 512.0f) + 1e-5f);
  const int cb = lane * 8;
#pragma unroll
  for (int t = 0; t < 8; ++t) {
    float xv = (v[t] - mu) * rs * g[cb + t] + be[cb + t];
    of[base + t] = xv;
    ob[base + t] = f2bf(xv);
  }
}

// ---------------------------------------------------------------------------
// LN2: out = LN(f0 + f1 + b2 + x)
// ---------------------------------------------------------------------------
__global__ __launch_bounds__(256) void ln2_kernel(
    const float* __restrict__ f0, const u16* __restrict__ f1,
    const float* __restrict__ b2, const float* __restrict__ bsrc,
    const float* __restrict__ g, const float* __restrict__ be,
    float* __restrict__ of)
{
  const int row = blockIdx.x * 4 + (threadIdx.x >> 6);
  const int lane = threadIdx.x & 63;
  const size_t base = (size_t)row * 512 + lane * 8;
  const int cb = lane * 8;
  float v[8];
#pragma unroll
  for (int t = 0; t < 8; ++t)
    v[t] = f0[base + t] + bf2f(f1[base + t]) + b2[cb + t] + bsrc[base + t];
  float s = 0.f;
#pragma unroll
  for (int t = 0; t < 8; ++t) s += v[t];
#pragma unroll
  for (int off = 1; off < 64; off <<= 1) s += __shfl_xor(s, off, 64);
  const float mu = s * (1.0f / 512.0f);
  float qv = 0.f;
#pragma unroll
  for (int t = 0; t < 8; ++t) { float d = v[t] - mu; qv += d * d; }
#pragma unroll
  for (int off = 1; off < 64; off <<= 1) qv += __shfl_xor(qv, off, 64);
  const float rs = rsqrtf(qv * (1.0f / 512.0f) + 1e-5f);
#pragma unroll
  for (int t = 0; t < 8; ++t) {
    float xv = (v[t] - mu) * rs * g[cb + t] + be[cb + t];
    of[base + t] = xv;
  }
}

// ---------------------------------------------------------------------------
// prep kernels
// ---------------------------------------------------------------------------
__global__ __launch_bounds__(256) void cast_bf_kernel(
    const float* __restrict__ in, u16* __restrict__ out)
{
  const size_t i = ((size_t)blockIdx.x * 256 + threadIdx.x) * 8;
#pragma unroll
  for (int t = 0; t < 8; ++t) out[i + t] = f2bf(in[i + t]);
}

// Tiled transpose for the three 512x512 QKV weights in one launch (z = which).
__global__ __launch_bounds__(256) void transpose_qkv_kernel(
    const float* __restrict__ Wq, const float* __restrict__ Wk,
    const float* __restrict__ Wv, u16* __restrict__ dst)
{
  __shared__ u16 tile[32][33];
  const float* src = (blockIdx.z == 0) ? Wq : (blockIdx.z == 1) ? Wk : Wv;
  u16* d = dst + (size_t)blockIdx.z * 512 * 512;
  const int tx = threadIdx.x & 31, ty = threadIdx.x >> 5;
  const int n0 = blockIdx.x * 32, k0 = blockIdx.y * 32;
#pragma unroll
  for (int i = 0; i < 32; i += 8)
    tile[ty + i][tx] = f2bf(src[(size_t)(k0 + ty + i) * 512 + n0 + tx]);
  __syncthreads();
#pragma unroll
  for (int i = 0; i < 32; i += 8)
    d[(size_t)(n0 + ty + i) * 512 + k0 + tx] = tile[tx][ty + i];
}

__global__ __launch_bounds__(256) void transpose_bf_kernel(
    const float* __restrict__ src, u16* __restrict__ dst, int K, int N)
{
  __shared__ u16 tile[32][33];
  const int tx = threadIdx.x & 31, ty = threadIdx.x >> 5;
  const int n0 = blockIdx.x * 32, k0 = blockIdx.y * 32;
#pragma unroll
  for (int i = 0; i < 32; i += 8)
    tile[ty + i][tx] = f2bf(src[(size_t)(k0 + ty + i) * N + n0 + tx]);
  __syncthreads();
#pragma unroll
  for (int i = 0; i < 32; i += 8)
    dst[(size_t)(n0 + ty + i) * K + k0 + tx] = tile[tx][ty + i];
}

// ---------------------------------------------------------------------------
// launch
// ---------------------------------------------------------------------------
extern "C" void kernel_launch(void* const* d_in, const int* in_sizes, int n_in,
                              void* d_out, int out_size, void* d_ws, size_t ws_size,
                              hipStream_t stream) {
  const float* tokens = (const float*)d_in[0];
  const float* Wq = (const float*)d_in[1];
  const float* bq = (const float*)d_in[2];
  const float* Wk = (const float*)d_in[3];
  const float* bk = (const float*)d_in[4];
  const float* Wv = (const float*)d_in[5];
  const float* bv = (const float*)d_in[6];
  const float* dscale = (const float*)d_in[7];
  const float* W1 = (const float*)d_in[8];
  const float* b1 = (const float*)d_in[9];
  const float* W2 = (const float*)d_in[10];
  const float* b2 = (const float*)d_in[11];
  const float* g1 = (const float*)d_in[12];
  const float* be1 = (const float*)d_in[13];
  const float* g2 = (const float*)d_in[14];
  const float* be2 = (const float*)d_in[15];
  float* out = (float*)d_out;

  // Flat workspace layout (ws_size = 256 MiB). NO overlays.
  char* ws = (char*)d_ws;
  u16*   tok_bf = (u16*)(ws + 0);            //   8.4 MB
  u16*   wqkvT  = (u16*)(ws + 8388608);      //   1.6 MB
  u16*   w1T    = (u16*)(ws + 9961472);      //   2.1 MB
  u16*   w2T    = (u16*)(ws + 12058624);     //   2.1 MB
  u16*   qbuf   = (u16*)(ws + 14155776);     //   8.4 MB
  u16*   kbuf   = (u16*)(ws + 22544384);     //   8.4 MB
  u16*   vtbuf  = (u16*)(ws + 30932992);     //   8.4 MB
  u16*   Pbuf   = (u16*)(ws + 39321600);     //  64   MB (2 batches)
  float* y0buf  = (float*)(ws + 106430464);  //  16.8 MB
  u16*   y1buf  = (u16*)(ws + 123207680);    //   8.4 MB
  u16*   y2buf  = (u16*)(ws + 131596288);    //   8.4 MB
  u16*   y3buf  = (u16*)(ws + 139984896);    //   8.4 MB
  float* xf     = (float*)(ws + 148373504);  //  16.8 MB
  u16*   xbf    = (u16*)(ws + 165150720);    //   8.4 MB
  u16*   hbuf   = (u16*)(ws + 173539328);    //  33.6 MB
  float* f0buf  = (float*)(ws + 207093760);  //  16.8 MB
  u16*   f1buf  = (u16*)(ws + 223870976);    //   8.4 MB
  float* lbuf   = (float*)(ws + 232259584);  //  32 KB (ends 232292352)
  u16*   vbuf   = (u16*)(ws + 232292352);    //   8.4 MB (ends 240680960 < 256 MiB)

  (void)hipMemsetAsync(lbuf, 0, 2 * 4096 * sizeof(float), stream);
  // y1/y2/y3 need no memset: ln1 reads them only for rows gemm_pv wrote.

  cast_bf_kernel<<<2048, 256, 0, stream>>>(tokens, tok_bf);
  transpose_qkv_kernel<<<dim3(16, 16, 3), 256, 0, stream>>>(Wq, Wk, Wv, wqkvT);
  transpose_bf_kernel<<<dim3(64, 16), 256, 0, stream>>>(W1, w1T, 512, 2048);
  transpose_bf_kernel<<<dim3(16, 64), 256, 0, stream>>>(W2, w2T, 2048, 512);

  gemm_qkv<<<dim3(12, 64), 256, 0, stream>>>(tok_bf, wqkvT, bq, bk, bv, qbuf, kbuf, vbuf);
  transpose_v_kernel<<<dim3(128, 16, 2), 256, 0, stream>>>(vbuf, vtbuf);

  // attention: both batches per launch
  gemm_qk_p<<<dim3(528, 2), 256, 0, stream>>>(qbuf, kbuf, dscale, Pbuf, lbuf);
  gemm_pv<<<dim3(4, 80, 2), 256, 0, stream>>>(Pbuf, vtbuf, y0buf, y1buf, y2buf, y3buf);

  ln1_kernel<<<2048, 256, 0, stream>>>(y0buf, y1buf, y2buf, y3buf, lbuf, tokens,
                                       g1, be1, xf, xbf);

  gemm_ffn1<<<dim3(16, 64), 256, 0, stream>>>(xbf, w1T, b1, hbuf);

  gemm_ffn2<<<dim3(4, 64, 2), 256, 0, stream>>>(hbuf, w2T, f0buf, f1buf);

  ln2_kernel<<<2048, 256, 0, stream>>>(f0buf, f1buf, b2, xf, g2, be2, out);
}